// Round 11
// baseline (611.458 us; speedup 1.0000x reference)
//
#include <hip/hip_runtime.h>
#include <hip/hip_bf16.h>

#define M_TOKENS 4096
#define K_IN     4096
#define N_OUT    11008

#define BM 256
#define BN 256
#define BK 64
#define KTILES (K_IN / BK)   // 64

typedef __bf16 bf16x8 __attribute__((ext_vector_type(8)));
typedef float  f32x4  __attribute__((ext_vector_type(4)));

__device__ __forceinline__ void async_copy16(const void* g, void* l) {
    __builtin_amdgcn_global_load_lds(
        (const __attribute__((address_space(1))) void*)g,
        (__attribute__((address_space(3))) void*)l, 16, 0, 0);
}

// ---- x fp32 -> bf16 cast, 8 elems/thread ----
__global__ __launch_bounds__(256) void cast_x_kernel(const float* __restrict__ x,
                                                     __hip_bfloat16* __restrict__ xb) {
    size_t idx = (size_t)blockIdx.x * 256 + threadIdx.x;
    const float4* xf = reinterpret_cast<const float4*>(x) + idx * 2;
    float4 a = xf[0], b = xf[1];
    float v[8] = {a.x, a.y, a.z, a.w, b.x, b.y, b.z, b.w};
    alignas(16) __hip_bfloat16 t[8];
#pragma unroll
    for (int j = 0; j < 8; ++j) t[j] = __float2bfloat16(v[j]);
    *reinterpret_cast<uint4*>(xb + idx * 8) = *reinterpret_cast<const uint4*>(t);
}

// ---- dequant to TILE-MAJOR bf16: WbT[kt][n][64], kt = k/64 ----
// Block: 256 thr = 32 n x 8 k-chunks. blockIdx = kt*344 + nblk (344 = 11008/32).
__global__ __launch_bounds__(256) void dequant_kernel(const int* __restrict__ wq,
                                                      const float* __restrict__ snz,
                                                      __hip_bfloat16* __restrict__ wbt) {
    int bid  = blockIdx.x;
    int kt   = bid / 344;
    int nblk = bid - kt * 344;
    int tid  = threadIdx.x;
    int n    = nblk * 32 + (tid >> 3);
    int k8l  = tid & 7;
    int k    = kt * 64 + k8l * 8;
    int g    = kt >> 1;                       // k/128, constant within block row
    const float* sz = snz + ((size_t)g * N_OUT + n) * 2;
    float scale = sz[0], zero = sz[1];
    const int4* q4 = reinterpret_cast<const int4*>(wq + (size_t)n * K_IN + k);
    int4 qa = q4[0], qb = q4[1];
    int q[8] = {qa.x, qa.y, qa.z, qa.w, qb.x, qb.y, qb.z, qb.w};
    alignas(16) __hip_bfloat16 t[8];
#pragma unroll
    for (int j = 0; j < 8; ++j)
        t[j] = __float2bfloat16((float)(q[j] - 8) * scale + zero);
    __hip_bfloat16* dst = wbt + ((size_t)kt * N_OUT + n) * 64 + k8l * 8;
    *reinterpret_cast<uint4*>(dst) = *reinterpret_cast<const uint4*>(t);
}

// ====== 256x256 bf16 GEMM — A via LDS (verified swizzle), B direct from tile-major ======
// R10 insight: DS pipe is INSTRUCTION-bound (~12 cyc/ds_read_b128). Both-operand
// LDS = 192 reads/tile = 2304 cyc vs MFMA 2483 -> serialized 4900 (all rounds).
// Here: B never touches LDS. WbT[kt][n][64] makes each B panel 32KB contiguous:
// B frag load = 16 full 128B lines/instr, L1-resident across the 4 sharing instrs.
// Per tile: DS = 128 reads (1536 cyc) < MFMA (2483); B = 8 VMEM loads/wave
// (~1100 cyc L2, separate pipe) -> MFMA-bound.
// Sync: vmcnt(8)+barrier (drains 4 A-stages only; 8 B-loads ride through) before
// reading the freshly staged buffer; plain end barrier (all CUR reads consumed
// pre-barrier via MFMA data-deps -> wait-then-barrier invariant holds).

#define SCB()  __builtin_amdgcn_sched_barrier(0)
#define VM8BAR() { SCB(); asm volatile("s_waitcnt vmcnt(8)" ::: "memory"); \
                   __builtin_amdgcn_s_barrier(); SCB(); }
#define ENDBAR() { SCB(); __builtin_amdgcn_s_barrier(); SCB(); }

#define RD_A(DST, T, HALF, KK) \
    _Pragma("unroll") for (int mi = 0; mi < 4; ++mi) DST[mi] = readA(T, (HALF) * 4 + mi, KK);

// B tile-major load: lane l: col = n0+wc*64+nf*16+(l&15), bytes kk*64 + (l>>4)*16
#define LOADB(DST, KT) \
    _Pragma("unroll") for (int nf = 0; nf < 4; ++nf) \
    _Pragma("unroll") for (int kk = 0; kk < 2; ++kk) { \
        const char* g = (const char*)WbT \
            + ((size_t)(KT) * N_OUT + (n0 + wc * 64 + nf * 16 + l15)) * 128 \
            + kk * 64 + kb16; \
        DST[nf][kk] = *(const bf16x8*)g; \
    }

#define MM16(AOFF, AF, BC, KK) \
    __builtin_amdgcn_s_setprio(1); \
    { \
        _Pragma("unroll") for (int mi = 0; mi < 4; ++mi) \
        _Pragma("unroll") for (int nf = 0; nf < 4; ++nf) \
            acc[AOFF + mi][nf] = __builtin_amdgcn_mfma_f32_16x16x32_bf16( \
                AF[mi], BC[nf][KK], acc[AOFF + mi][nf], 0, 0, 0); \
    } \
    __builtin_amdgcn_s_setprio(0);

// One K-tile. Entering: aX = CUR aL kk0 (read post-barrier last tile), BC landed.
#define TILE(CUR, ALT, BC, BN_, KN) \
    stageA(ALT, KN); \
    SCB();                       /* pin: 4 stages oldest in VMEM FIFO */ \
    LOADB(BN_, KN); \
    RD_A(aY, CUR, 1, 0); \
    MM16(0, aX, BC, 0); \
    RD_A(aX, CUR, 0, 1); \
    MM16(4, aY, BC, 0); \
    RD_A(aY, CUR, 1, 1); \
    MM16(0, aX, BC, 1); \
    VM8BAR();                    /* ALT staged & visible; B loads still flying */ \
    RD_A(aX, ALT, 0, 0); \
    MM16(4, aY, BC, 1); \
    ENDBAR();                    /* CUR reads all consumed; safe to re-stage */

__global__ __launch_bounds__(512, 2) void gemm_bd_kernel(
        const __hip_bfloat16* __restrict__ Xb,
        const __hip_bfloat16* __restrict__ WbT,
        float* __restrict__ C) {
    __shared__ alignas(16) char smem[65536];   // A only: 2 x [256 rows][128B]

    const int tid  = threadIdx.x;
    const int lane = tid & 63;
    const int wave = tid >> 6;
    const int wr   = wave >> 2;     // 0..1  (M half)
    const int wc   = wave & 3;      // 0..3  (N quarter)
    const int l15  = lane & 15;
    const int kb16 = ((lane >> 4) << 4);   // 16B k-group offset
    const int lrow = lane >> 3;     // staging row-in-chunk
    const int ssw  = (((lane & 7) ^ lrow) << 4);   // pre-swizzled source col (bytes)

    // XCD-bijective swizzle (grid = 688, 688 % 8 == 0)
    unsigned bid = blockIdx.x;
    unsigned per = gridDim.x >> 3;               // 86
    unsigned swz = (bid & 7u) * per + (bid >> 3);
    const int tn = (int)(swz % (N_OUT / BN));    // 43
    const int tm = (int)(swz / (N_OUT / BN));    // 16
    const int m0 = tm * BM;
    const int n0 = tn * BN;

    // swizzled read column (bytes within a 128B row); kk toggles bit 6
    const int colswz = (((lane >> 4) << 4) ^ ((lane & 7) << 4));

    f32x4 acc[8][4];
#pragma unroll
    for (int i = 0; i < 8; ++i)
#pragma unroll
        for (int j = 0; j < 4; ++j) {
            f32x4 z = {0.f, 0.f, 0.f, 0.f};
            acc[i][j] = z;
        }
    bf16x8 aX[4], aY[4], bX[4][2], bY[4][2];

    // stage a full 32KB A-tile (4 x global_load_lds/thread, 8 rows per chunk)
    auto stageA = [&](char* dstTile, int kt) {
#pragma unroll
        for (int j = 0; j < 4; ++j) {
            int rb = (wave * 4 + j) * 8;
            const char* g = (const char*)Xb + ((size_t)(m0 + rb + lrow) * K_IN) * 2
                            + (size_t)kt * 128 + ssw;
            async_copy16(g, dstTile + rb * 128);
        }
    };
    auto readA = [&](char* tile, int mi8, int kk) -> bf16x8 {
        return *(const bf16x8*)(tile + (wr * 128 + mi8 * 16 + l15) * 128 + (colswz ^ (kk << 6)));
    };

    char* const A0 = smem;   char* const A1 = smem + 32768;

    // ---- prologue: stage A(t0); load B(t0); drain stages; pre-read aL kk0 ----
    stageA(A0, 0);
    SCB();
    LOADB(bX, 0);
    VM8BAR();
    RD_A(aX, A0, 0, 0);

    for (int i = 0; i < KTILES / 2; ++i) {
        const int k1 = (2 * i + 1) & (KTILES - 1);
        const int k2 = (2 * i + 2) & (KTILES - 1);   // wraps on last iter: dead ops, harmless
        TILE(A0, A1, bX, bY, k1)
        TILE(A1, A0, bY, bX, k2)
    }

    // ---- epilogue: D layout col=lane&15, row=(lane>>4)*4+e ----
    const int r4 = (lane >> 4) << 2;
#pragma unroll
    for (int mi = 0; mi < 8; ++mi)
#pragma unroll
        for (int nf = 0; nf < 4; ++nf)
#pragma unroll
            for (int e = 0; e < 4; ++e) {
                int row = m0 + wr * 128 + mi * 16 + r4 + e;
                int col = n0 + wc * 64 + nf * 16 + l15;
                C[(size_t)row * N_OUT + col] = acc[mi][nf][e];
            }
}

extern "C" void kernel_launch(void* const* d_in, const int* in_sizes, int n_in,
                              void* d_out, int out_size, void* d_ws, size_t ws_size,
                              hipStream_t stream) {
    const float* x   = (const float*)d_in[0];
    const int*   wq  = (const int*)d_in[1];
    const float* snz = (const float*)d_in[2];
    float* out = (float*)d_out;

    __hip_bfloat16* Xb  = (__hip_bfloat16*)d_ws;                                        // 32 MB
    __hip_bfloat16* WbT = (__hip_bfloat16*)((char*)d_ws + (size_t)M_TOKENS * K_IN * 2); // 86 MB

    cast_x_kernel<<<(M_TOKENS * (size_t)K_IN) / 8 / 256, 256, 0, stream>>>(x, Xb);
    dequant_kernel<<<KTILES * (N_OUT / 32), 256, 0, stream>>>(wq, snz, WbT);
    gemm_bd_kernel<<<(M_TOKENS / BM) * (N_OUT / BN), 512, 0, stream>>>(Xb, WbT, out);
}

// Round 12
// 247.839 us; speedup vs baseline: 2.4672x; 2.4672x over previous
//
#include <hip/hip_runtime.h>
#include <hip/hip_bf16.h>
#include <math.h>

#define M_TOKENS 4096
#define K_IN     4096
#define N_OUT    11008

#define BM 256
#define BN 256
#define BK 128
#define KTILES (K_IN / BK)   // 32

typedef int i32x4 __attribute__((ext_vector_type(4)));

__device__ __forceinline__ void async_copy16(const void* g, void* l) {
    __builtin_amdgcn_global_load_lds(
        (const __attribute__((address_space(1))) void*)g,
        (__attribute__((address_space(3))) void*)l, 16, 0, 0);
}

// ---- x fp32 -> int8, per-row (token) scale ----
__global__ __launch_bounds__(256) void quant_x_kernel(const float* __restrict__ x,
                                                      char* __restrict__ xq,
                                                      float* __restrict__ xs) {
    __shared__ float wmax[4];
    const int m = blockIdx.x;
    const int t = threadIdx.x;
    const float* row = x + (size_t)m * K_IN;
    float4 v[4];
    float lmax = 0.f;
#pragma unroll
    for (int p = 0; p < 4; ++p) {
        v[p] = *reinterpret_cast<const float4*>(row + p * 1024 + t * 4);
        lmax = fmaxf(lmax, fmaxf(fmaxf(fabsf(v[p].x), fabsf(v[p].y)),
                                 fmaxf(fabsf(v[p].z), fabsf(v[p].w))));
    }
#pragma unroll
    for (int off = 32; off >= 1; off >>= 1)
        lmax = fmaxf(lmax, __shfl_xor(lmax, off, 64));
    if ((t & 63) == 0) wmax[t >> 6] = lmax;
    __syncthreads();
    float gmax = fmaxf(fmaxf(wmax[0], wmax[1]), fmaxf(wmax[2], wmax[3]));
    gmax = fmaxf(gmax, 1e-20f);
    const float inv = 127.f / gmax;
    if (t == 0) xs[m] = gmax / 127.f;
#pragma unroll
    for (int p = 0; p < 4; ++p) {
        float vv[4] = {v[p].x, v[p].y, v[p].z, v[p].w};
        alignas(4) char c[4];
#pragma unroll
        for (int j = 0; j < 4; ++j) {
            float q = rintf(vv[j] * inv);
            q = fminf(fmaxf(q, -127.f), 127.f);
            c[j] = (char)(int)q;
        }
        *reinterpret_cast<unsigned*>(xq + (size_t)m * K_IN + p * 1024 + t * 4) =
            *reinterpret_cast<const unsigned*>(c);
    }
}

// ---- per-column weight scale, exact from (s,z): max_g max(|z-8s|,|z+7s|) ----
__global__ __launch_bounds__(256) void scale_w_kernel(const float* __restrict__ snz,
                                                      float* __restrict__ ws,
                                                      float* __restrict__ wsinv) {
    int n = blockIdx.x * 256 + threadIdx.x;
    if (n >= N_OUT) return;
    float m = 0.f;
#pragma unroll 4
    for (int g = 0; g < 32; ++g) {
        float s = snz[((size_t)g * N_OUT + n) * 2];
        float z = snz[((size_t)g * N_OUT + n) * 2 + 1];
        m = fmaxf(m, fmaxf(fabsf(z - 8.f * s), fabsf(z + 7.f * s)));
    }
    m = fmaxf(m, 1e-20f);
    ws[n] = m / 127.f;
    wsinv[n] = 127.f / m;
}

// ---- int4-code dequant -> int8 [n][k] (B^T layout), 8 k/thread ----
__global__ __launch_bounds__(256) void dequant_kernel(const int* __restrict__ wq,
                                                      const float* __restrict__ snz,
                                                      const float* __restrict__ wsinv,
                                                      char* __restrict__ wb) {
    size_t idx = (size_t)blockIdx.x * 256 + threadIdx.x;   // n*(K/8) + k8
    int n  = (int)(idx >> 9);         // K_IN/8 = 512
    int k8 = (int)(idx & 511);
    int g  = k8 >> 4;                 // (k8*8)/128
    const float* sz = snz + ((size_t)g * N_OUT + n) * 2;
    float scale = sz[0], zero = sz[1];
    float inv = wsinv[n];
    const int4* q4 = reinterpret_cast<const int4*>(wq + (size_t)n * K_IN + (size_t)k8 * 8);
    int4 qa = q4[0], qb = q4[1];
    int q[8] = {qa.x, qa.y, qa.z, qa.w, qb.x, qb.y, qb.z, qb.w};
    alignas(8) char t[8];
#pragma unroll
    for (int j = 0; j < 8; ++j) {
        float w = (float)(q[j] - 8) * scale + zero;
        float qq = rintf(w * inv);
        qq = fminf(fmaxf(qq, -127.f), 127.f);
        t[j] = (char)(int)qq;
    }
    *reinterpret_cast<uint2*>(wb + idx * 8) = *reinterpret_cast<const uint2*>(t);
}

// ====== 256x256 int8 GEMM — R4's proven kk-balanced 4-phase schedule, BK=128 ======
// i8 mfma_i32_16x16x64: K=64/instr at 2x bf16 rate, exact i32 accumulation.
// BK=128 keeps LDS rows at 128 BYTES -> ALL addressing (stage units, XOR swizzle,
// read slots) byte-identical to the round-4 kernel that passed at 352us.
// K-tiles halve (32): per-tile DS(2304)+MFMA(~2600) serialized cost is the same,
// but half as many tiles -> ~2x GEMM speedup without a schedule breakthrough.
// Fragment layout (analog of m89-verified bf16 16x16x32): row=lane&15,
// k = (lane>>4)*16 + j (16 contiguous bytes/lane). C/D layout dtype-independent
// (m121/m127): col=lane&15, row=(lane>>4)*4+e. Epilogue: f32 = acc*xs[row]*ws[col].

#define SCB()  __builtin_amdgcn_sched_barrier(0)
#define SBAR() { SCB(); __builtin_amdgcn_s_barrier(); SCB(); }
#define LGKM0() { asm volatile("s_waitcnt lgkmcnt(0)" ::: "memory"); SCB(); }
#define VM4()  { asm volatile("s_waitcnt vmcnt(4)" ::: "memory"); SCB(); }

#define RD_AL(T, S) \
    _Pragma("unroll") for (int mi = 0; mi < 4; ++mi) aL[mi] = readA(T, mi, S);
#define RD_AH(T, S) \
    _Pragma("unroll") for (int mi = 0; mi < 4; ++mi) aH[mi] = readA(T, 4 + mi, S);
#define RD_B4(T, S) \
    _Pragma("unroll") for (int ni = 0; ni < 4; ++ni) bk[ni] = readB(T, ni, S);

#define MFMA16(AOFF, FRAG) \
    __builtin_amdgcn_s_setprio(1); \
    { \
        _Pragma("unroll") for (int mi = 0; mi < 4; ++mi) \
        _Pragma("unroll") for (int ni = 0; ni < 4; ++ni) \
            acc[AOFF + mi][ni] = __builtin_amdgcn_mfma_i32_16x16x64_i8( \
                FRAG[mi], bk[ni], acc[AOFF + mi][ni], 0, 0, 0); \
    } \
    __builtin_amdgcn_s_setprio(0);

// One K-tile: consume (CA,CB); stage next-tile units into (NA,NB); K1=t+1, K2=t+2.
#define TILE(CA, CB, NA, NB, K1, K2) \
    /* phA: aL x b (s0); drained by previous end-of-phD VM4 */ \
    RD_AL(CA, 0); RD_B4(CB, 0); \
    stageB(NB, K1, 1); \
    SBAR(); LGKM0(); \
    MFMA16(0, aL); \
    VM4(); SBAR();   /* drains CAu1 for phB */ \
    /* phB */ \
    RD_AH(CA, 0); \
    stageA(NA, K1, 0); \
    SBAR(); LGKM0(); \
    MFMA16(4, aH); \
    SBAR(); \
    /* phC: s1 of already-guaranteed data */ \
    RD_AL(CA, 1); RD_B4(CB, 1); \
    stageA(NA, K1, 1); \
    SBAR(); LGKM0(); \
    MFMA16(0, aL); \
    SBAR(); \
    /* phD */ \
    RD_AH(CA, 1); \
    stageB(CB, K2, 0); \
    SBAR(); LGKM0(); \
    MFMA16(4, aH); \
    VM4(); SBAR();   /* drains NAu0, NBu0, NBu1 for next tile's phA */

__global__ __launch_bounds__(512, 2) void gemm_i8_kernel(
        const char* __restrict__ Xq,
        const char* __restrict__ Wq,
        const float* __restrict__ xs,
        const float* __restrict__ ws,
        float* __restrict__ C) {
    __shared__ alignas(16) char smem[131072];
    char* const ldsA = smem;            // [2][256 rows][128 i8 = 128B]
    char* const ldsB = smem + 65536;

    const int tid  = threadIdx.x;
    const int lane = tid & 63;
    const int wave = tid >> 6;
    const int wr   = wave >> 2;     // 0..1  (M half)
    const int wc   = wave & 3;      // 0..3  (N quarter)
    const int l15  = lane & 15;
    const int lrow = lane >> 3;     // staging row-in-chunk
    const int ssw  = (((lane & 7) ^ lrow) << 4);   // pre-swizzled source col (bytes)

    // XCD-bijective swizzle (grid = 688, 688 % 8 == 0)
    unsigned bid = blockIdx.x;
    unsigned per = gridDim.x >> 3;               // 86
    unsigned swz = (bid & 7u) * per + (bid >> 3);
    const int tn = (int)(swz % (N_OUT / BN));    // 43
    const int tm = (int)(swz / (N_OUT / BN));    // 16
    const int m0 = tm * BM;
    const int n0 = tn * BN;

    // swizzled read column (bytes within a 128B row); K-step s toggles bit 6
    const int colswz = (((lane >> 4) << 4) ^ ((lane & 7) << 4));

    i32x4 acc[8][4];
#pragma unroll
    for (int i = 0; i < 8; ++i)
#pragma unroll
        for (int j = 0; j < 4; ++j) {
            i32x4 z = {0, 0, 0, 0};
            acc[i][j] = z;
        }
    i32x4 aL[4], aH[4], bk[4];

    // stage one 16KB unit (2 x global_load_lds/thread)
    auto stageA = [&](char* dstTile, int kt, int unit) {
#pragma unroll
        for (int j = 0; j < 2; ++j) {
            int c  = wave * 2 + j;
            int rb = (c >> 3) * 128 + (c & 7) * 8 + unit * 64;   // u0: rows 0-63,128-191
            const char* g = Xq + (size_t)(m0 + rb + lrow) * K_IN
                            + (size_t)kt * 128 + ssw;
            async_copy16(g, dstTile + rb * 128);
        }
    };
    auto stageB = [&](char* dstTile, int kt, int unit) {
#pragma unroll
        for (int j = 0; j < 2; ++j) {
            int c  = wave * 2 + j;
            int rb = (c >> 2) * 64 + (c & 3) * 8 + unit * 32;    // u0: rows 0-31 per 64-seg
            const char* g = Wq + (size_t)(n0 + rb + lrow) * K_IN
                            + (size_t)kt * 128 + ssw;
            async_copy16(g, dstTile + rb * 128);
        }
    };
    auto readA = [&](char* tile, int mi8, int s) -> i32x4 {
        return *(const i32x4*)(tile + (wr * 128 + mi8 * 16 + l15) * 128 + (colswz ^ (s << 6)));
    };
    auto readB = [&](char* tile, int ni4, int s) -> i32x4 {
        return *(const i32x4*)(tile + (wc * 64 + ni4 * 16 + l15) * 128 + (colswz ^ (s << 6)));
    };

    char* const A0 = ldsA;   char* const A1 = ldsA + 32768;
    char* const B0 = ldsB;   char* const B1 = ldsB + 32768;

    // ---- prologue: [B0u0, B0u1, A0u0, A0u1, B1u0]; drain first 3 units ----
    stageB(B0, 0, 0); stageB(B0, 0, 1); stageA(A0, 0, 0); stageA(A0, 0, 1);
    stageB(B1, 1, 0);
    VM4(); SBAR();

    for (int i = 0; i < KTILES / 2; ++i) {
        const int k1 = (2 * i + 1) & (KTILES - 1);
        const int k2 = (2 * i + 2) & (KTILES - 1);
        const int k3 = (2 * i + 3) & (KTILES - 1);   // wraps on last iters: dead-but-safe
        TILE(A0, B0, A1, B1, k1, k2)   // tile 2i   (buf0)
        TILE(A1, B1, A0, B0, k2, k3)   // tile 2i+1 (buf1)
    }

    // ---- epilogue: D layout col=lane&15, row=(lane>>4)*4+e; scale by xs*ws ----
    const int r4 = (lane >> 4) << 2;
    float sn[4];
#pragma unroll
    for (int nf = 0; nf < 4; ++nf) sn[nf] = ws[n0 + wc * 64 + nf * 16 + l15];
#pragma unroll
    for (int mi = 0; mi < 8; ++mi) {
        const float4 xm = *reinterpret_cast<const float4*>(xs + m0 + wr * 128 + mi * 16 + r4);
        const float xv[4] = {xm.x, xm.y, xm.z, xm.w};
#pragma unroll
        for (int nf = 0; nf < 4; ++nf)
#pragma unroll
            for (int e = 0; e < 4; ++e) {
                int row = m0 + wr * 128 + mi * 16 + r4 + e;
                int col = n0 + wc * 64 + nf * 16 + l15;
                C[(size_t)row * N_OUT + col] = (float)acc[mi][nf][e] * xv[e] * sn[nf];
            }
    }
}

extern "C" void kernel_launch(void* const* d_in, const int* in_sizes, int n_in,
                              void* d_out, int out_size, void* d_ws, size_t ws_size,
                              hipStream_t stream) {
    const float* x   = (const float*)d_in[0];
    const int*   wq  = (const int*)d_in[1];
    const float* snz = (const float*)d_in[2];
    float* out = (float*)d_out;

    char*  Xq    = (char*)d_ws;                                   // 16 MB
    char*  Wq8   = (char*)d_ws + ((size_t)M_TOKENS * K_IN);       // 43 MB
    float* xs    = (float*)((char*)d_ws + (size_t)M_TOKENS * K_IN + (size_t)N_OUT * K_IN);
    float* ws    = xs + M_TOKENS;
    float* wsinv = ws + N_OUT;

    quant_x_kernel<<<M_TOKENS, 256, 0, stream>>>(x, Xq, xs);
    scale_w_kernel<<<(N_OUT + 255) / 256, 256, 0, stream>>>(snz, ws, wsinv);
    dequant_kernel<<<((size_t)N_OUT * K_IN) / 8 / 256, 256, 0, stream>>>(wq, snz, wsinv, Wq8);
    gemm_i8_kernel<<<(M_TOKENS / BM) * (N_OUT / BN), 512, 0, stream>>>(Xq, Wq8, xs, ws, out);
}